// Round 7
// baseline (284.502 us; speedup 1.0000x reference)
//
#include <hip/hip_runtime.h>

// VectorQuantizer forward: out = codebook[argmin_k ||x - e_k||^2]
// R13: R12 (fp16 single-term scores) resubmitted with graph-capture risks
//      removed: no hipMemsetAsync in kernel_launch, no cross-block atomics.
//      Per-dim error weights emax/lemax now come from a tiny dedicated
//      kernel vq_eps (1 block x 64 threads, each thread scans 512 codes).
//      Rationale (R12): R9/R10 showed per-CU time is invariant to occupancy
//      and schedule -> only total pipe work moves this kernel. fp16 x.e:
//      products exact in fp32, so error is input rounding only, bounded
//      per-row by sum(|x-h(x)|*emax_d + |h(x)|*lemax_d). MFMA per ct:
//      12 -> 4; B-pack LDS: 128 -> 64 KB -> 2 blocks/CU (512-thr blocks).
//      Rows failing gap - 2*eps_row > MARGIN (covers fp32-accum worst case)
//      take the unchanged exact-fp32 first-min fallback => committed
//      argmins provably identical to fp32 path.

#define KC 512
#define DD 64
#define MARGIN 2.5e-4f   // c-space margin: fp32 accum worst-case + ref-rounding

typedef __attribute__((ext_vector_type(8))) short short8;
typedef _Float16 half8 __attribute__((ext_vector_type(8)));
typedef __attribute__((ext_vector_type(4))) float float4v;

// Per-dim error weights over the whole codebook: emax[d] = max_k |E[d][k]|,
// lemax[d] = max_k |E[d][k] - fp16(E[d][k])|. 1 block x 64 threads.
__global__ __launch_bounds__(64) void vq_eps(const float* __restrict__ emb,
                                             float* __restrict__ emax,
                                             float* __restrict__ lemax) {
    const int d = threadIdx.x;            // 0..63
    float em = 0.f, lm = 0.f;
    for (int k = 0; k < KC; k += 4) {
        float4 v = *(const float4*)(emb + (size_t)d * KC + k);
        float f[4] = {v.x, v.y, v.z, v.w};
        #pragma unroll
        for (int j = 0; j < 4; ++j) {
            _Float16 h = (_Float16)f[j];
            em = fmaxf(em, fabsf(f[j]));
            lm = fmaxf(lm, fabsf(f[j] - (float)h));
        }
    }
    emax[d]  = em;
    lemax[d] = lm;
}

// Per code-tile ct (16 codes): bias (exact fp32, sequential d), et (fp32
// transposed codebook for gather/fallback), Bf fp16 pack in the exact
// 16x16x32 B-fragment order: element (lane l, j) = E[kc*32 + (l>>4)*8 + j]
// [ct*16 + (l&15)].
__global__ __launch_bounds__(256) void vq_prep(const float* __restrict__ emb,
                                               float* __restrict__ et,
                                               float* __restrict__ bias,
                                               short* __restrict__ Bf) {
    __shared__ float tile[DD][17];
    const int ct = blockIdx.x;            // 0..31
    const int t  = threadIdx.x;

    {   // stage emb[d][ct*16..+16] -> tile[d][c]
        const int d = t >> 2, c0 = (t & 3) * 4;
        float4 v = *(const float4*)(emb + (size_t)d * KC + ct * 16 + c0);
        tile[d][c0 + 0] = v.x; tile[d][c0 + 1] = v.y;
        tile[d][c0 + 2] = v.z; tile[d][c0 + 3] = v.w;
    }
    __syncthreads();

    if (t < 16) {   // bias, exact sequential d-order
        float s = 0.f;
        #pragma unroll
        for (int d = 0; d < DD; ++d) { float v = tile[d][t]; s += v * v; }
        bias[ct * 16 + t] = s;
    }

    {   // et[(ct*16+c)][d0..d0+3]
        const int c = t >> 4, d0 = (t & 15) * 4;
        float4 v;
        v.x = tile[d0 + 0][c]; v.y = tile[d0 + 1][c];
        v.z = tile[d0 + 2][c]; v.w = tile[d0 + 3][c];
        *(float4*)(et + (size_t)(ct * 16 + c) * DD + d0) = v;
    }

    if (t < 128) {   // fp16 B-fragment pack
        const int kc = t >> 6, l = t & 63;
        const int c  = l & 15, dq = l >> 4;
        short v8[8];
        #pragma unroll
        for (int j = 0; j < 8; ++j) {
            float f = tile[kc * 32 + dq * 8 + j][c];
            _Float16 h = (_Float16)f;
            v8[j] = __builtin_bit_cast(short, h);
        }
        *(short8*)(Bf + ((size_t)(ct * 2 + kc) * 64 + l) * 8) = *(short8*)v8;
    }
}

// Block = 512 threads / 8 waves, covers 256 rows; wave w owns rows
// [w*32, w*32+32) in registers (fp16 A-frags) and sweeps all 512 codes
// from a 64 KB LDS copy of Bf. ~70 KB LDS -> 2 blocks/CU.
__global__ __launch_bounds__(512, 4) void vq_main(const float* __restrict__ x_in,
                                                  const short* __restrict__ Bf,
                                                  const float* __restrict__ bias,
                                                  const float* __restrict__ emax,
                                                  const float* __restrict__ lemax,
                                                  const float* __restrict__ et,
                                                  float* __restrict__ out) {
    __shared__ __align__(16) short Bf_lds[32 * 2 * 64 * 8];   // 64 KB
    __shared__ float bias_s[KC];                               // 2 KB
    __shared__ float eps_s[8][32];
    __shared__ int   k1s[8][32];
    __shared__ float gaps[8][32];

    const int t = threadIdx.x, w = t >> 6, l = t & 63;
    const int col = l & 15, quad = l >> 4;
    const int R0 = blockIdx.x * 256;
    const int wrow0 = w * 32;

    {   // stage Bf/bias -> LDS (coalesced float4 copies)
        const float4* src = (const float4*)Bf;
        float4* dst = (float4*)Bf_lds;
        #pragma unroll
        for (int j = 0; j < 8; ++j) {
            const int idx = t + j * 512;              // 4096 float4 total
            dst[idx] = src[idx];
        }
        bias_s[t] = bias[t];
    }

    // ---- error weights for this lane's dims (d = kc*32 + quad*8 + j)
    float em[2][8], lm[2][8];
    #pragma unroll
    for (int kc = 0; kc < 2; ++kc) {
        float4 a = *(const float4*)(emax + kc * 32 + quad * 8);
        float4 b = *(const float4*)(emax + kc * 32 + quad * 8 + 4);
        em[kc][0] = a.x; em[kc][1] = a.y; em[kc][2] = a.z; em[kc][3] = a.w;
        em[kc][4] = b.x; em[kc][5] = b.y; em[kc][6] = b.z; em[kc][7] = b.w;
        float4 c = *(const float4*)(lemax + kc * 32 + quad * 8);
        float4 d = *(const float4*)(lemax + kc * 32 + quad * 8 + 4);
        lm[kc][0] = c.x; lm[kc][1] = c.y; lm[kc][2] = c.z; lm[kc][3] = c.w;
        lm[kc][4] = d.x; lm[kc][5] = d.y; lm[kc][6] = d.z; lm[kc][7] = d.w;
    }

    // ---- A: this wave's 32 rows -> fp16 registers + per-row error bound.
    // 16x16x32 A-layout: m = lane&15, k = quad*8 + j; rt = 16-row tile 0..1.
    half8 AF[2][2];
    float errp[2] = {0.f, 0.f};
    #pragma unroll
    for (int rt = 0; rt < 2; ++rt)
        #pragma unroll
        for (int kc = 0; kc < 2; ++kc) {
            const float* p = x_in + (size_t)(R0 + wrow0 + rt * 16 + col) * DD
                           + kc * 32 + quad * 8;
            float4 xa = *(const float4*)p;
            float4 xb = *(const float4*)(p + 4);
            float f[8] = {xa.x, xa.y, xa.z, xa.w, xb.x, xb.y, xb.z, xb.w};
            #pragma unroll
            for (int j = 0; j < 8; ++j) {
                _Float16 h = (_Float16)f[j];
                AF[rt][kc][j] = h;
                float fh = (float)h;
                errp[rt] = fmaf(fabsf(f[j] - fh), em[kc][j], errp[rt]);
                errp[rt] = fmaf(fabsf(fh),        lm[kc][j], errp[rt]);
            }
        }
    // row (l&15) of tile rt: sum partials across the 4 quads
    #pragma unroll
    for (int rt = 0; rt < 2; ++rt) {
        errp[rt] += __shfl_xor(errp[rt], 16, 64);
        errp[rt] += __shfl_xor(errp[rt], 32, 64);
    }
    if (quad == 0) {
        eps_s[w][col]      = errp[0];
        eps_s[w][16 + col] = errp[1];
    }
    __syncthreads();   // B staged (the only block-wide barrier)

    // per-(row,code-lane) running max1/max2/k in c-space (c = x.e - b/2)
    float m1[2][4], m2[2][4];
    int   kb[2][4];
    #pragma unroll
    for (int rt = 0; rt < 2; ++rt)
        #pragma unroll
        for (int r = 0; r < 4; ++r) {
            m1[rt][r] = -3.4e38f; m2[rt][r] = -3.4e38f; kb[rt][r] = 0;
        }

    #pragma unroll 2
    for (int ct = 0; ct < 32; ++ct) {
        half8 bf0 = *(const half8*)&Bf_lds[((ct * 2 + 0) * 64 + l) * 8];
        half8 bf1 = *(const half8*)&Bf_lds[((ct * 2 + 1) * 64 + l) * 8];
        const float ci = -0.5f * bias_s[ct * 16 + col];
        const int kk = ct * 16 + col;
        #pragma unroll
        for (int rt = 0; rt < 2; ++rt) {
            float4v c = {ci, ci, ci, ci};
            c = __builtin_amdgcn_mfma_f32_16x16x32_f16(AF[rt][0], bf0, c, 0, 0, 0);
            c = __builtin_amdgcn_mfma_f32_16x16x32_f16(AF[rt][1], bf1, c, 0, 0, 0);
            #pragma unroll
            for (int r = 0; r < 4; ++r) {
                float cr = c[r];
                bool gt = cr > m1[rt][r];                    // strict: first-min k
                m2[rt][r] = fmaxf(fminf(cr, m1[rt][r]), m2[rt][r]);
                kb[rt][r] = gt ? kk : kb[rt][r];
                m1[rt][r] = fmaxf(m1[rt][r], cr);
            }
        }
    }

    // reduce over the 16 code-lanes (once per wave); C layout: row =
    // rt*16 + quad*4 + r, col = lane&15.
    #pragma unroll
    for (int rt = 0; rt < 2; ++rt)
        #pragma unroll
        for (int r = 0; r < 4; ++r) {
            float b1 = m1[rt][r], b2 = m2[rt][r];
            int   bk = kb[rt][r];
            #pragma unroll
            for (int m = 1; m <= 8; m <<= 1) {
                float o1 = __shfl_xor(b1, m, 64);
                float o2 = __shfl_xor(b2, m, 64);
                int   ok = __shfl_xor(bk, m, 64);
                float n2 = fmaxf(fmaxf(b2, o2), fminf(b1, o1));
                bool take = (o1 > b1) || (o1 == b1 && ok < bk);
                b1 = take ? o1 : b1;
                bk = take ? ok : bk;
                b2 = n2;
            }
            if (col == 0) {
                const int rowl = rt * 16 + quad * 4 + r;
                k1s[w][rowl]  = bk;
                // safe iff (b1-b2) - 2*eps_row > MARGIN
                gaps[w][rowl] = (b1 - b2) - 2.f * eps_s[w][rowl];
            }
        }

    {   // exact fp32 fallback for rows whose gap is within the error bound.
        // Lane l scans codes [8l,8l+8) ascending; cross-lane tie-break =
        // lower k => numpy first-min semantics, independent of approx path.
        unsigned long long mask = __ballot((l < 32) && (gaps[w][l & 31] <= MARGIN));
        mask &= 0xFFFFFFFFull;
        while (mask) {
            const int rr = __builtin_ctzll(mask);
            mask &= mask - 1;
            const size_t grow = (size_t)(R0 + wrow0 + rr) * DD;
            const int kbase = l * 8;
            float acc[8];
            #pragma unroll
            for (int j = 0; j < 8; ++j) acc[j] = 0.f;
            for (int d0 = 0; d0 < DD; d0 += 4) {
                float4 xv = *(const float4*)(x_in + grow + d0);
                #pragma unroll
                for (int j = 0; j < 8; ++j) {
                    float4 ev = *(const float4*)(et + (size_t)(kbase + j) * DD + d0);
                    acc[j] += xv.x * ev.x;
                    acc[j] += xv.y * ev.y;
                    acc[j] += xv.z * ev.z;
                    acc[j] += xv.w * ev.w;
                }
            }
            float4 b0 = *(const float4*)(bias + kbase);
            float4 b1v = *(const float4*)(bias + kbase + 4);
            float bb[8] = {b0.x, b0.y, b0.z, b0.w, b1v.x, b1v.y, b1v.z, b1v.w};
            float bv = 3.4e38f; int bk = 0;
            #pragma unroll
            for (int j = 0; j < 8; ++j) {
                float s = bb[j] - 2.f * acc[j];
                if (s < bv) { bv = s; bk = kbase + j; }
            }
            #pragma unroll
            for (int m = 1; m <= 32; m <<= 1) {
                float ov = __shfl_xor(bv, m, 64);
                int   ok = __shfl_xor(bk, m, 64);
                if (ov < bv || (ov == bv && ok < bk)) { bv = ov; bk = ok; }
            }
            if (l == 0) k1s[w][rr] = bk;
        }
    }

    {   // gather epilogue (per wave, its own rows): 16 lanes per row
        const int c4 = col * 4;
        #pragma unroll
        for (int i = 0; i < 8; ++i) {
            const int rowl = i * 4 + quad;
            const int bk = k1s[w][rowl];
            float4 v = *(const float4*)(et + (size_t)bk * DD + c4);
            *(float4*)(out + (size_t)(R0 + wrow0 + rowl) * DD + c4) = v;
        }
    }
}

extern "C" void kernel_launch(void* const* d_in, const int* in_sizes, int n_in,
                              void* d_out, int out_size, void* d_ws, size_t ws_size,
                              hipStream_t stream) {
    const float* x_in = (const float*)d_in[0];   // [131072, 64]
    const float* emb  = (const float*)d_in[1];   // [64, 512]
    float* out = (float*)d_out;

    float* et    = (float*)d_ws;                      // 512*64 f32 = 131072 B
    float* bias  = et + KC * DD;                      // 2048 B
    short* Bf    = (short*)(bias + KC);               // 32*2*64*8 shorts = 64 KB
    float* emax  = (float*)(Bf + 32 * 2 * 64 * 8);    // 256 B
    float* lemax = emax + DD;                         // 256 B

    const int N = out_size / DD;                      // 131072 rows

    vq_eps<<<1, 64, 0, stream>>>(emb, emax, lemax);
    vq_prep<<<32, 256, 0, stream>>>(emb, et, bias, Bf);
    vq_main<<<N / 256, 512, 0, stream>>>(x_in, Bf, bias, emax, lemax, et, out);
}